// Round 1
// baseline (2381.611 us; speedup 1.0000x reference)
//
#include <hip/hip_runtime.h>

#define BATCH 4096
#define T 512
#define ISZ 63
#define H 32
#define CT 8   // timesteps staged per chunk

// 3 waves per block: wave 0 = z-gate, wave 1 = r-gate, wave 2 = h-gate.
// Lane = (bsub in {0,1}, j in 0..31). Each lane holds its gate's weight
// column (63 x-weights + 32 h-weights) in VGPRs for the whole T loop.
// h/z/(r*h) are exchanged through LDS with broadcast (same-address) reads.
__global__ __launch_bounds__(192, 3) void gru_fused(
    const float* __restrict__ x,
    const float* __restrict__ w_xz, const float* __restrict__ w_hz, const float* __restrict__ b_z,
    const float* __restrict__ w_xr, const float* __restrict__ w_hr, const float* __restrict__ b_r,
    const float* __restrict__ w_xh, const float* __restrict__ w_hh, const float* __restrict__ b_h,
    const float* __restrict__ w_out, const float* __restrict__ b_out,
    float* __restrict__ out)
{
    __shared__ __align__(16) float x_lds[2][CT][64];   // 63 used, 64 stride for alignment
    __shared__ __align__(16) float h_lds[2][H];
    __shared__ __align__(16) float z_lds[2][H];
    __shared__ __align__(16) float rh_lds[2][H];

    const int tid  = threadIdx.x;
    const int wav  = tid >> 6;          // 0=z, 1=r, 2=h
    const int bsub = (tid >> 5) & 1;
    const int j    = tid & 31;

    const float* wxp = (wav == 0) ? w_xz : (wav == 1) ? w_xr : w_xh;
    const float* whp = (wav == 0) ? w_hz : (wav == 1) ? w_hr : w_hh;
    const float* bp  = (wav == 0) ? b_z  : (wav == 1) ? b_r  : b_h;

    // Register-resident weight columns (one-time coalesced loads).
    float wx[ISZ];
    float wh[H];
    #pragma unroll
    for (int i = 0; i < ISZ; ++i) wx[i] = wxp[i * H + j];
    #pragma unroll
    for (int k = 0; k < H; ++k)  wh[k] = whp[k * H + j];
    const float bias = bp[j];

    for (int pair = 0; pair < 2; ++pair) {
        const int b0 = blockIdx.x * 4 + pair * 2;   // this team-step handles b0, b0+1

        if (tid < 64) h_lds[tid >> 5][tid & 31] = 0.f;
        __syncthreads();

        for (int c = 0; c < T / CT; ++c) {
            // ---- stage CT timesteps of x for both batches (coalesced) ----
            const size_t gbase = ((size_t)b0 * T + (size_t)c * CT) * ISZ;
            for (int idx = tid; idx < 2 * CT * ISZ; idx += 192) {
                int bb = idx / (CT * ISZ);
                int f  = idx - bb * (CT * ISZ);       // 0..503, contiguous in global
                int tt = f / ISZ;
                int ii = f - tt * ISZ;
                x_lds[bb][tt][ii] = x[gbase + (size_t)bb * (T * ISZ) + f];
            }
            __syncthreads();

            for (int tt = 0; tt < CT; ++tt) {
                // ---- phase 1: x-dot (all waves); z/r: + h-dot, sigmoid ----
                float acc = bias;
                const float4* xr4 = (const float4*)(&x_lds[bsub][tt][0]);
                #pragma unroll
                for (int i4 = 0; i4 < 15; ++i4) {
                    float4 v = xr4[i4];
                    acc = fmaf(v.x, wx[4*i4+0], acc);
                    acc = fmaf(v.y, wx[4*i4+1], acc);
                    acc = fmaf(v.z, wx[4*i4+2], acc);
                    acc = fmaf(v.w, wx[4*i4+3], acc);
                }
                acc = fmaf(x_lds[bsub][tt][60], wx[60], acc);
                acc = fmaf(x_lds[bsub][tt][61], wx[61], acc);
                acc = fmaf(x_lds[bsub][tt][62], wx[62], acc);

                if (wav < 2) {
                    const float4* hr4 = (const float4*)(&h_lds[bsub][0]);
                    #pragma unroll
                    for (int k4 = 0; k4 < 8; ++k4) {
                        float4 v = hr4[k4];
                        acc = fmaf(v.x, wh[4*k4+0], acc);
                        acc = fmaf(v.y, wh[4*k4+1], acc);
                        acc = fmaf(v.z, wh[4*k4+2], acc);
                        acc = fmaf(v.w, wh[4*k4+3], acc);
                    }
                    float s = __fdividef(1.f, 1.f + __expf(-acc));
                    if (wav == 0) z_lds[bsub][j] = s;                     // z
                    else          rh_lds[bsub][j] = s * h_lds[bsub][j];   // r*h
                }
                __syncthreads();

                // ---- phase 2: h-wave: (r*h)-dot, tanh, blend, update h ----
                if (wav == 2) {
                    const float4* rr4 = (const float4*)(&rh_lds[bsub][0]);
                    #pragma unroll
                    for (int k4 = 0; k4 < 8; ++k4) {
                        float4 v = rr4[k4];
                        acc = fmaf(v.x, wh[4*k4+0], acc);
                        acc = fmaf(v.y, wh[4*k4+1], acc);
                        acc = fmaf(v.z, wh[4*k4+2], acc);
                        acc = fmaf(v.w, wh[4*k4+3], acc);
                    }
                    float e    = __expf(-2.f * acc);
                    float htld = __fdividef(1.f - e, 1.f + e);            // tanh(acc)
                    float zval = z_lds[bsub][j];
                    float hold = h_lds[bsub][j];
                    h_lds[bsub][j] = fmaf(zval, htld - hold, hold);       // (1-z)h + z*ht
                }
                __syncthreads();
            }
        }

        // ---- output: sigmoid(h @ w_out + b_out) ----
        if (wav == 2) {
            float p = h_lds[bsub][j] * w_out[j];
            #pragma unroll
            for (int off = 16; off >= 1; off >>= 1) p += __shfl_xor(p, off);
            if (j == 0) out[b0 + bsub] = __fdividef(1.f, 1.f + __expf(-(p + b_out[0])));
        }
        __syncthreads();   // protect h_lds/x_lds before next pair
    }
}

extern "C" void kernel_launch(void* const* d_in, const int* in_sizes, int n_in,
                              void* d_out, int out_size, void* d_ws, size_t ws_size,
                              hipStream_t stream) {
    const float* x     = (const float*)d_in[0];
    const float* w_xz  = (const float*)d_in[1];
    const float* w_hz  = (const float*)d_in[2];
    const float* b_z   = (const float*)d_in[3];
    const float* w_xr  = (const float*)d_in[4];
    const float* w_hr  = (const float*)d_in[5];
    const float* b_r   = (const float*)d_in[6];
    const float* w_xh  = (const float*)d_in[7];
    const float* w_hh  = (const float*)d_in[8];
    const float* b_h   = (const float*)d_in[9];
    const float* w_out = (const float*)d_in[10];
    const float* b_out = (const float*)d_in[11];
    float* out = (float*)d_out;

    dim3 grid(BATCH / 4), block(192);
    hipLaunchKernelGGL(gru_fused, grid, block, 0, stream,
                       x, w_xz, w_hz, b_z, w_xr, w_hr, b_r,
                       w_xh, w_hh, b_h, w_out, b_out, out);
}